// Round 7
// baseline (232.412 us; speedup 1.0000x reference)
//
#include <hip/hip_runtime.h>

// Problem constants (from reference setup_inputs)
#define BB   64          // batch
#define SS   512         // seq len
#define HH   768         // hidden dim
#define WW   256         // MAX_WORD_LEN (words per batch)
#define WE   300         // word-embedding dim
#define OUTD (HH + WE)   // 1068 output feature dim

// mean kernel: 16-token slab per block, DMA'd to LDS
#define NR         32                 // slabs per batch row
#define TR         (SS / NR)          // 16 tokens per slab
#define SLAB_B     (TR * HH * 4)      // 49152 B = 48 KiB
// w2v kernel: 16 lanes per word
#define LPW        16
#define WPB2       (256 / LPW)        // 16 words per block
#define WGPB2      (WW / WPB2)        // 16 groups per row -> 1024 blocks

// R7: R0-R6 all consumed `hidden` via per-thread VGPR loads; the register
// allocator provably (VGPR=32-36 every round) serialized them into
// load->wait->add chains (1 load in flight/thread) -> pinned at ~2.7 TB/s
// effective while the harness's own fill proves 6.6 TB/s is reachable.
// Fix: global_load_lds DMA — fire-and-forget, NO destination VGPR, so the
// allocator cannot re-serialize it. Per block: issue 12x4KiB DMA of a
// contiguous slab, do token staging + LB scatter under the DMA flight time,
// one barrier, then consume from LDS (69 TB/s) with simple per-word loops.
// Inter-block overlap (3 blocks/CU at 51 KiB LDS) pipelines DMA phases.

// ---------------- kernel 1: segment means -> out[:,:,0:768] ----------------
__global__ __launch_bounds__(256)
void EmbeddingsModule_45311904973549_mean(
    const float* __restrict__ hidden,     // [B, S, H]
    const int*   __restrict__ token_ids,  // [B, S] sorted per row, in [0,W)
    float*       __restrict__ out)        // [B, W, OUTD]
{
    __shared__ float4 slab[TR * HH / 4];  // 48 KiB, linear copy of the slab
    __shared__ int    tk[SS];
    __shared__ int    LB[WW + 1];         // LB[k] = lower_bound(k) this row

    const int b    = blockIdx.x / NR;
    const int r    = blockIdx.x % NR;
    const int s0   = r * TR;
    const int tid  = threadIdx.x;
    const int wave = tid >> 6;
    const int lane = tid & 63;

    // --- 1) issue slab DMA: 12 chunks of 4 KiB (1 KiB per wave per chunk).
    // LDS dest is wave-uniform base + lane*16 (HW rule); global src per-lane.
    const char* gsrc = (const char*)(hidden + ((size_t)b * SS + s0) * HH);
    #pragma unroll
    for (int it = 0; it < SLAB_B / 4096; ++it) {
        const int off = it * 4096 + wave * 1024;
        __builtin_amdgcn_global_load_lds(
            (const unsigned int*)(gsrc + off + lane * 16),
            (unsigned int*)((char*)slab + off),
            16, 0, 0);
    }

    // --- 2) stage token row + LB init (overlaps the DMA flight)
    ((int2*)tk)[tid] = ((const int2*)(token_ids + (size_t)b * SS))[tid];
    LB[tid] = SS;
    if (tid == 0) LB[WW] = SS;
    __syncthreads();          // drains DMA (vmcnt 0) + tk writes

    // --- 3) scatter lower bounds: pos s with t=tk[s], tp=tk[s-1] sets
    //        LB[k]=s for k in (tp, t]; each LB[k] written by <=1 thread.
    #pragma unroll
    for (int u = 0; u < 2; ++u) {
        const int s  = tid * 2 + u;
        const int t  = tk[s];
        const int tp = (s == 0) ? -1 : tk[s - 1];
        for (int k = tp + 1; k <= t; ++k) LB[k] = s;
    }
    __syncthreads();

    // --- 4) word range owned by this block: (w_prev, wlast]
    const int w_prev = (r == 0) ? -1 : tk[s0 - 1];
    const int wlast  = (r == NR - 1) ? (WW - 1) : tk[s0 + TR - 1];
    if (wlast == w_prev) return;          // no word starts in this slab
    if (tid >= 192) return;               // wave 3: staging only

    float* const  outb = out + (size_t)b * WW * OUTD;
    const float4* hrow = (const float4*)(hidden + (size_t)b * SS * HH);
    const int     send = s0 + TR;

    // --- 5) per-word consume from LDS. Only w==wlast can spill past the
    //        slab (hi > send); its tail reads global (rare, avg seg len 2).
    for (int w = w_prev + 1; w <= wlast; ++w) {
        const int lo = __builtin_amdgcn_readfirstlane(LB[w]);
        const int hi = __builtin_amdgcn_readfirstlane(LB[w + 1]);
        float4 acc = make_float4(0.f, 0.f, 0.f, 0.f);
        const int hs = (hi < send) ? hi : send;
        for (int s = lo; s < hs; ++s) {
            const float4 v = slab[(s - s0) * (HH / 4) + tid];
            acc.x += v.x; acc.y += v.y; acc.z += v.z; acc.w += v.w;
        }
        for (int s = send; s < hi; ++s) {     // global tail (w==wlast only)
            const float4 v = hrow[(size_t)s * (HH / 4) + tid];
            acc.x += v.x; acc.y += v.y; acc.z += v.z; acc.w += v.w;
        }
        const float inv = (hi > lo) ? (1.0f / (float)(hi - lo)) : 0.0f;
        acc.x *= inv; acc.y *= inv; acc.z *= inv; acc.w *= inv;
        ((float4*)(outb + (size_t)w * OUTD))[tid] = acc;  // out[b,w,0:768]
    }
}

// ---------------- kernel 2: w2v gather -> out[:,:,768:1068] ----------------
__global__ __launch_bounds__(256)
void EmbeddingsModule_45311904973549_w2v(
    const float* __restrict__ w2v,        // [VOCAB, WE]
    const int*   __restrict__ word_ids,   // [B, W] in [0,VOCAB)
    float*       __restrict__ out)        // [B, W, OUTD]
{
    const int b   = blockIdx.x / WGPB2;
    const int g   = blockIdx.x % WGPB2;
    const int w   = g * WPB2 + (threadIdx.x >> 4);  // 16 words x 16 lanes
    const int l   = threadIdx.x & 15;
    const int wid = word_ids[b * WW + w];
    const float4* src = (const float4*)(w2v + (size_t)wid * WE);
    float4*       dst = (float4*)(out + (size_t)(b * WW + w) * OUTD + HH);
    float4 t[5];
    #pragma unroll
    for (int i = 0; i < 4; ++i) t[i] = src[l + 16 * i];  // j = 0..63
    if (l < (WE / 4 - 64)) t[4] = src[64 + l];           // j = 64..74
    #pragma unroll
    for (int i = 0; i < 4; ++i) dst[l + 16 * i] = t[i];
    if (l < (WE / 4 - 64)) dst[64 + l] = t[4];
}

extern "C" void kernel_launch(void* const* d_in, const int* in_sizes, int n_in,
                              void* d_out, int out_size, void* d_ws, size_t ws_size,
                              hipStream_t stream) {
    const float* hidden    = (const float*)d_in[0];
    const float* w2v       = (const float*)d_in[1];
    const int*   token_ids = (const int*)d_in[2];
    const int*   word_ids  = (const int*)d_in[3];
    float*       out       = (float*)d_out;

    EmbeddingsModule_45311904973549_mean<<<BB * NR, 256, 0, stream>>>(
        hidden, token_ids, out);
    EmbeddingsModule_45311904973549_w2v<<<BB * WGPB2, 256, 0, stream>>>(
        w2v, word_ids, out);
}

// Round 8
// 207.638 us; speedup vs baseline: 1.1193x; 1.1193x over previous
//
#include <hip/hip_runtime.h>

// Problem constants (from reference setup_inputs)
#define BB   64          // batch
#define SS   512         // seq len
#define HH   768         // hidden dim
#define WW   256         // MAX_WORD_LEN (words per batch)
#define WE   300         // word-embedding dim
#define OUTD (HH + WE)   // 1068 output feature dim
#define LBS  (WW + 1)    // bounds-table stride per batch row (257)

// R8: R0 (16384 tiny blocks) remains the empirical champion (64.5us vs
// 69-89us for every "smarter" structure, R1-R7). Its modeled critical path
// is ~60% binary search: 18 DEPENDENT token_ids loads (~3000cy) recomputed
// per block, vs ~2 hidden loads (~1400cy) of actual work. This round keeps
// R0's exact structure and removes only the search: kernel A precomputes
// lower bounds LB[b][w] once (64 blocks, LDS scatter, 66KB table in d_ws);
// kernel B = R0 with the search replaced by two independent scalar loads
// LB[w], LB[w+1] (~200cy L2-hot), plus a 2-way unrolled mean loop (8 VGPRs
// of batch - small enough that the allocator keeps both loads in flight).

// ---------------- kernel A: per-(b,w) lower bounds -> d_ws ----------------
__global__ __launch_bounds__(256)
void EmbeddingsModule_45311904973549_bounds(
    const int* __restrict__ token_ids,   // [B, S] sorted per row, in [0,W)
    int*       __restrict__ LBg)         // [B, 257]
{
    __shared__ int tk[SS];
    __shared__ int LB[LBS];

    const int b   = blockIdx.x;
    const int tid = threadIdx.x;

    ((int2*)tk)[tid] = ((const int2*)(token_ids + (size_t)b * SS))[tid];
    LB[tid] = SS;
    if (tid == 0) LB[WW] = SS;
    __syncthreads();

    // scatter: position s with t=tk[s], tp=tk[s-1] (tp=-1 at s=0) sets
    // LB[k]=s for k in (tp, t]; ranges are disjoint across s -> no race.
    #pragma unroll
    for (int u = 0; u < 2; ++u) {
        const int s  = tid * 2 + u;
        const int t  = tk[s];
        const int tp = (s == 0) ? -1 : tk[s - 1];
        for (int k = tp + 1; k <= t; ++k) LB[k] = s;
    }
    __syncthreads();

    LBg[b * LBS + tid] = LB[tid];
    if (tid == 0) LBg[b * LBS + WW] = LB[WW];
}

// ------------- kernel B: R0 structure, bounds from table ------------------
// One block per (b,w). Waves 0-2 (192 threads): segment mean of hidden over
// [lo,hi) -> out[b,w,0:768]. Wave 3: w2v row copy -> out[b,w,768:1068].
__global__ __launch_bounds__(256)
void EmbeddingsModule_45311904973549_kernel(
    const float* __restrict__ hidden,     // [B, S, H]
    const float* __restrict__ w2v,        // [VOCAB, WE]
    const int*   __restrict__ LBg,        // [B, 257] lower bounds
    const int*   __restrict__ word_ids,   // [B, W] in [0,VOCAB)
    float*       __restrict__ out)        // [B, W, OUTD]
{
    const int bw  = blockIdx.x;       // 0 .. B*W-1
    const int b   = bw >> 8;          // / WW
    const int w   = bw & (WW - 1);    // % WW
    const int tid = threadIdx.x;

    float* orow = out + (size_t)bw * OUTD;

    if (tid < 192) {
        // two INDEPENDENT scalar loads (uniform address -> s_load), no chain
        const int lo = LBg[b * LBS + w];
        const int hi = LBg[b * LBS + w + 1];
        const int cnt = hi - lo;
        const float inv = (cnt > 0) ? (1.0f / (float)cnt) : 0.0f;

        const float4* hrow = (const float4*)(hidden + (size_t)b * SS * HH);
        float4 a0 = make_float4(0.f, 0.f, 0.f, 0.f);
        float4 a1 = make_float4(0.f, 0.f, 0.f, 0.f);
        int s = lo;
        for (; s + 1 < hi; s += 2) {          // 2 loads in flight per iter
            float4 v0 = hrow[(size_t)s       * (HH / 4) + tid];
            float4 v1 = hrow[(size_t)(s + 1) * (HH / 4) + tid];
            a0.x += v0.x; a0.y += v0.y; a0.z += v0.z; a0.w += v0.w;
            a1.x += v1.x; a1.y += v1.y; a1.z += v1.z; a1.w += v1.w;
        }
        if (s < hi) {
            float4 v0 = hrow[(size_t)s * (HH / 4) + tid];
            a0.x += v0.x; a0.y += v0.y; a0.z += v0.z; a0.w += v0.w;
        }
        float4 acc = make_float4((a0.x + a1.x) * inv, (a0.y + a1.y) * inv,
                                 (a0.z + a1.z) * inv, (a0.w + a1.w) * inv);
        ((float4*)orow)[tid] = acc;     // out[b,w, 0:768]
    } else {
        // w2v gather: 75 float4s with 64 threads (j and j+64), as in R0
        const int     wid  = word_ids[bw];
        const float4* wrow = (const float4*)(w2v + (size_t)wid * WE);
        float4*       grow = (float4*)(orow + HH);   // out[b,w, 768:1068]
        for (int j = tid - 192; j < WE / 4; j += 64) {
            grow[j] = wrow[j];
        }
    }
}

extern "C" void kernel_launch(void* const* d_in, const int* in_sizes, int n_in,
                              void* d_out, int out_size, void* d_ws, size_t ws_size,
                              hipStream_t stream) {
    const float* hidden    = (const float*)d_in[0];
    const float* w2v       = (const float*)d_in[1];
    const int*   token_ids = (const int*)d_in[2];
    const int*   word_ids  = (const int*)d_in[3];
    float*       out       = (float*)d_out;
    int*         LBg       = (int*)d_ws;    // 64*257*4 = 65,792 B

    EmbeddingsModule_45311904973549_bounds<<<BB, 256, 0, stream>>>(
        token_ids, LBg);
    EmbeddingsModule_45311904973549_kernel<<<BB * WW, 256, 0, stream>>>(
        hidden, w2v, LBg, word_ids, out);
}